// Round 3
// baseline (3217.719 us; speedup 1.0000x reference)
//
#include <hip/hip_runtime.h>
#include <hip/hip_bf16.h>
#include <math.h>

typedef __attribute__((ext_vector_type(4))) float f32x4;
typedef __attribute__((ext_vector_type(8))) short s16x8;
typedef __attribute__((ext_vector_type(4))) unsigned short u16x4;

#define MFMA16(a, b, c) __builtin_amdgcn_mfma_f32_16x16x32_bf16(a, b, c, 0, 0, 0)

static constexpr int BB = 32, TT = 128, EE = 512, HH = 1024, VV = 32000;
static constexpr int FH = 4 * HH;           // 4096 gate rows
static constexpr int MROWS = (TT - 1) * BB; // 4064 valid rows
static constexpr int MPAD = 4096;
static constexpr int BH = BB * HH;          // 32768
static constexpr int NBLK = 256;            // persistent grid

__device__ __forceinline__ unsigned short f2bf(float f) {
  unsigned int u = __float_as_uint(f);
  u = (u + 0x7FFFu + ((u >> 16) & 1u)) >> 16;
  return (unsigned short)u;
}
__device__ __forceinline__ float sigf(float x) { return 1.f / (1.f + __expf(-x)); }

__device__ __forceinline__ s16x8 pack8f(const float* p) {
  float4 x = *(const float4*)p;
  float4 y = *(const float4*)(p + 4);
  s16x8 r;
  r[0] = (short)f2bf(x.x); r[1] = (short)f2bf(x.y);
  r[2] = (short)f2bf(x.z); r[3] = (short)f2bf(x.w);
  r[4] = (short)f2bf(y.x); r[5] = (short)f2bf(y.y);
  r[6] = (short)f2bf(y.z); r[7] = (short)f2bf(y.w);
  return r;
}

__device__ __forceinline__ void gl_lds16(const void* g, void* l) {
  __builtin_amdgcn_global_load_lds(
      (const __attribute__((address_space(1))) unsigned int*)g,
      (__attribute__((address_space(3))) unsigned int*)l, 16, 0, 0);
}

// ---------------- zero / convert / embed ----------------

__global__ void zero_k(uint4* __restrict__ p, int n16) {
  int i = blockIdx.x * blockDim.x + threadIdx.x;
  int stride = gridDim.x * blockDim.x;
  uint4 z = {0u, 0u, 0u, 0u};
  for (; i < n16; i += stride) p[i] = z;
}

__global__ void cvt_bf16_v4(const float4* __restrict__ in, u16x4* __restrict__ out, int n4) {
  int i = blockIdx.x * blockDim.x + threadIdx.x;
  int stride = gridDim.x * blockDim.x;
  for (; i < n4; i += stride) {
    float4 v = in[i];
    u16x4 o;
    o[0] = f2bf(v.x); o[1] = f2bf(v.y); o[2] = f2bf(v.z); o[3] = f2bf(v.w);
    out[i] = o;
  }
}

__global__ __launch_bounds__(256) void embed_k(const int* __restrict__ captions,
                                               const float* __restrict__ etab,
                                               const float* __restrict__ pos,
                                               unsigned short* __restrict__ X) {
  const int m = blockIdx.x;  // row = t*32 + b
  const int t = m >> 5, b = m & 31;
  if (t < TT - 1) {
    const int tok = captions[b * TT + t];
    const float* er = etab + (size_t)tok * EE;
    for (int e = threadIdx.x; e < EE; e += 256)
      X[(size_t)m * EE + e] = f2bf(er[e] + pos[e]);
  } else {
    for (int e = threadIdx.x; e < EE; e += 256) X[(size_t)m * EE + e] = 0;
  }
}

__global__ void zero_out_t0(float* __restrict__ out) {
  out[(size_t)blockIdx.y * TT * VV + blockIdx.x * 256 + threadIdx.x] = 0.f;
}

// ---------------- C = A @ B^T bf16 MFMA GEMM, m97-style staging ----------------

__global__ __launch_bounds__(256) void gemm_bt(const unsigned short* __restrict__ A,
                                               const unsigned short* __restrict__ Bm,
                                               int K, int N, int mode,
                                               const float* __restrict__ bias0,
                                               const float* __restrict__ bias1,
                                               float* __restrict__ Cout) {
  __shared__ unsigned short As[128 * 64];
  __shared__ unsigned short Bs[128 * 64];
  const int tid = threadIdx.x;
  const int lane = tid & 63, wave = tid >> 6;
  const int wm = wave & 1, wn = wave >> 1;
  const int m0 = blockIdx.x * 128, n0 = blockIdx.y * 128;
  const int sch = (lane & 7) * 8;
  const int srbase = wave * 32 + (lane >> 3);
  f32x4 acc[4][4] = {};

  for (int k0 = 0; k0 < K; k0 += 64) {
    __syncthreads();
#pragma unroll
    for (int i = 0; i < 4; ++i) {
      const int r = srbase + i * 8;
      gl_lds16(&A[(size_t)(m0 + r) * K + k0 + sch], &As[(wave * 4 + i) * 512]);
      gl_lds16(&Bm[(size_t)(n0 + r) * K + k0 + sch], &Bs[(wave * 4 + i) * 512]);
    }
    __syncthreads();
#pragma unroll
    for (int kk = 0; kk < 64; kk += 32) {
      s16x8 af[4], bf[4];
#pragma unroll
      for (int f = 0; f < 4; ++f) {
        af[f] = *(const s16x8*)(&As[(wm * 64 + f * 16 + (lane & 15)) * 64 + kk + (lane >> 4) * 8]);
        bf[f] = *(const s16x8*)(&Bs[(wn * 64 + f * 16 + (lane & 15)) * 64 + kk + (lane >> 4) * 8]);
      }
#pragma unroll
      for (int mi = 0; mi < 4; ++mi)
#pragma unroll
        for (int ni = 0; ni < 4; ++ni)
          acc[mi][ni] = MFMA16(af[mi], bf[ni], acc[mi][ni]);
    }
  }

#pragma unroll
  for (int mi = 0; mi < 4; ++mi) {
#pragma unroll
    for (int ni = 0; ni < 4; ++ni) {
      const int col = n0 + wn * 64 + ni * 16 + (lane & 15);
      float bs = bias0[col] + (bias1 ? bias1[col] : 0.f);
      const int mbase = m0 + wm * 64 + mi * 16 + (lane >> 4) * 4;
#pragma unroll
      for (int r = 0; r < 4; ++r) {
        int m = mbase + r;
        if (m < MROWS) {
          float v = acc[mi][ni][r] + bs;
          if (mode == 0) {
            Cout[(size_t)m * N + col] = v;
          } else {
            int t = m >> 5, b = m & 31;
            Cout[((size_t)b * TT + (t + 1)) * VV + col] = v;
          }
        }
      }
    }
  }
}

// ---------------- persistent 2-layer LSTM, weights in registers ----------------
// Flag-array grid barrier: NO atomic RMW. Arrival = release store to own slot;
// completion = wave0 reads all 256 flags and spins on __all(min >= t+1).

__device__ __forceinline__ void flagbar(unsigned int* __restrict__ flags, unsigned int target) {
  __syncthreads();  // all waves' stores drained (vmcnt(0) before s_barrier)
  if (threadIdx.x == 0)
    __hip_atomic_store(&flags[blockIdx.x], target, __ATOMIC_RELEASE, __HIP_MEMORY_SCOPE_AGENT);
  if (threadIdx.x < 64) {
    const int base = (int)threadIdx.x * 4;
    for (;;) {
      unsigned m0 = __hip_atomic_load(&flags[base + 0], __ATOMIC_RELAXED, __HIP_MEMORY_SCOPE_AGENT);
      unsigned m1 = __hip_atomic_load(&flags[base + 1], __ATOMIC_RELAXED, __HIP_MEMORY_SCOPE_AGENT);
      unsigned m2 = __hip_atomic_load(&flags[base + 2], __ATOMIC_RELAXED, __HIP_MEMORY_SCOPE_AGENT);
      unsigned m3 = __hip_atomic_load(&flags[base + 3], __ATOMIC_RELAXED, __HIP_MEMORY_SCOPE_AGENT);
      unsigned mn = min(min(m0, m1), min(m2, m3));
      if (__all(mn >= target)) break;
      __builtin_amdgcn_s_sleep(1);
    }
    __builtin_amdgcn_fence(__ATOMIC_ACQUIRE, "agent");
  }
  __syncthreads();
}

__global__ __launch_bounds__(256, 1) void lstm_persist(
    const float* __restrict__ Whh0f, const float* __restrict__ Wih1f,
    const float* __restrict__ Whh1f, const float* __restrict__ G0pre,
    const float* __restrict__ bih1, const float* __restrict__ bhh1,
    unsigned short* __restrict__ h0buf, unsigned short* __restrict__ hs_all,
    unsigned int* __restrict__ flags) {
  __shared__ float parts[4][2][2][16][16];  // [wave][ah][fi][row16][col16] 8KB
  const int bid = blockIdx.x;
  const int layer = bid >> 7;     // 0:L0 1:L1
  const int blk = bid & 127;
  const int tid = threadIdx.x, lane = tid & 63, wave = tid >> 6;
  const int jb = blk * 8;
  const int colIdx = lane & 15;
  const int kq = lane >> 4;                                 // 0..3
  const int wrow0 = (colIdx >> 3) * HH + jb + (colIdx & 7); // + fi*2*HH -> W row

  const int cb = tid >> 3, cjj = tid & 7;
  float creg = 0.f;
  float bsum[4];
  if (layer == 1) {
#pragma unroll
    for (int gi = 0; gi < 4; ++gi)
      bsum[gi] = bih1[gi * HH + jb + cjj] + bhh1[gi * HH + jb + cjj];
  }

  // ---- preload weights into registers (fp32 -> bf16) ----
  s16x8 wreg[16][2];
  const int kb = (layer == 0) ? wave * 256 : (wave & 1) * 512;
  if (layer == 0) {
#pragma unroll
    for (int fi = 0; fi < 2; ++fi) {
      const float* wp = Whh0f + (size_t)(wrow0 + fi * 2 * HH) * HH + kb + kq * 8;
#pragma unroll
      for (int ks = 0; ks < 8; ++ks) wreg[ks][fi] = pack8f(wp + ks * 32);
    }
  } else {
    const float* Wsrc = (wave < 2) ? Wih1f : Whh1f;
#pragma unroll
    for (int fi = 0; fi < 2; ++fi) {
      const float* wp = Wsrc + (size_t)(wrow0 + fi * 2 * HH) * HH + kb + kq * 8;
#pragma unroll
      for (int ks = 0; ks < 16; ++ks) wreg[ks][fi] = pack8f(wp + ks * 32);
    }
  }

  for (int t = 0; t < TT; ++t) {
    if (layer == 0) {
      if (t < TT - 1) {
        float gpre[4];
#pragma unroll
        for (int gi = 0; gi < 4; ++gi)
          gpre[gi] = G0pre[((size_t)t * BB + cb) * FH + gi * HH + jb + cjj];

        const unsigned short* h0read = h0buf + (size_t)(t & 1) * BH;
        const unsigned short* a0 = h0read + (size_t)(lane & 15) * HH + kb + kq * 8;
        const unsigned short* a1 = a0 + 16 * HH;
        f32x4 acc00 = {}, acc01 = {}, acc10 = {}, acc11 = {};
#pragma unroll
        for (int ks = 0; ks < 8; ++ks) {
          s16x8 av0 = *(const s16x8*)(a0 + ks * 32);
          s16x8 av1 = *(const s16x8*)(a1 + ks * 32);
          acc00 = MFMA16(av0, wreg[ks][0], acc00);
          acc01 = MFMA16(av0, wreg[ks][1], acc01);
          acc10 = MFMA16(av1, wreg[ks][0], acc10);
          acc11 = MFMA16(av1, wreg[ks][1], acc11);
        }
#pragma unroll
        for (int r = 0; r < 4; ++r) {
          parts[wave][0][0][kq * 4 + r][colIdx] = acc00[r];
          parts[wave][0][1][kq * 4 + r][colIdx] = acc01[r];
          parts[wave][1][0][kq * 4 + r][colIdx] = acc10[r];
          parts[wave][1][1][kq * 4 + r][colIdx] = acc11[r];
        }
        __syncthreads();
        float g[4];
#pragma unroll
        for (int gi = 0; gi < 4; ++gi) {
          float s = gpre[gi];
          const int fi = gi >> 1, c = (gi & 1) * 8 + cjj;
#pragma unroll
          for (int w4 = 0; w4 < 4; ++w4) s += parts[w4][cb >> 4][fi][cb & 15][c];
          g[gi] = s;
        }
        const float i_ = sigf(g[0]), f_ = sigf(g[1]), gg = tanhf(g[2]), o_ = sigf(g[3]);
        creg = f_ * creg + i_ * gg;
        h0buf[(size_t)((t + 1) & 1) * BH + (size_t)cb * HH + jb + cjj] =
            f2bf(o_ * tanhf(creg));
      }
    } else {
      if (t >= 1) {
        const unsigned short* h0read = h0buf + (size_t)(t & 1) * BH;
        const unsigned short* Arow =
            (wave < 2) ? h0read : (hs_all + (size_t)(t - 1) * BH);
        const unsigned short* a0 = Arow + (size_t)(lane & 15) * HH + kb + kq * 8;
        const unsigned short* a1 = a0 + 16 * HH;
        f32x4 acc00 = {}, acc01 = {}, acc10 = {}, acc11 = {};
#pragma unroll
        for (int ks = 0; ks < 16; ++ks) {
          s16x8 av0 = *(const s16x8*)(a0 + ks * 32);
          s16x8 av1 = *(const s16x8*)(a1 + ks * 32);
          acc00 = MFMA16(av0, wreg[ks][0], acc00);
          acc01 = MFMA16(av0, wreg[ks][1], acc01);
          acc10 = MFMA16(av1, wreg[ks][0], acc10);
          acc11 = MFMA16(av1, wreg[ks][1], acc11);
        }
#pragma unroll
        for (int r = 0; r < 4; ++r) {
          parts[wave][0][0][kq * 4 + r][colIdx] = acc00[r];
          parts[wave][0][1][kq * 4 + r][colIdx] = acc01[r];
          parts[wave][1][0][kq * 4 + r][colIdx] = acc10[r];
          parts[wave][1][1][kq * 4 + r][colIdx] = acc11[r];
        }
        __syncthreads();
        float g[4];
#pragma unroll
        for (int gi = 0; gi < 4; ++gi) {
          float s = bsum[gi];
          const int fi = gi >> 1, c = (gi & 1) * 8 + cjj;
#pragma unroll
          for (int w4 = 0; w4 < 4; ++w4) s += parts[w4][cb >> 4][fi][cb & 15][c];
          g[gi] = s;
        }
        const float i_ = sigf(g[0]), f_ = sigf(g[1]), gg = tanhf(g[2]), o_ = sigf(g[3]);
        creg = f_ * creg + i_ * gg;
        hs_all[(size_t)t * BH + (size_t)cb * HH + jb + cjj] = f2bf(o_ * tanhf(creg));
      }
    }
    if (t < TT - 1) flagbar(flags, (unsigned int)(t + 1));
  }
}

// ---------------- host ----------------

extern "C" void kernel_launch(void* const* d_in, const int* in_sizes, int n_in,
                              void* d_out, int out_size, void* d_ws, size_t ws_size,
                              hipStream_t stream) {
  const int* captions = (const int*)d_in[1];
  const float* etab = (const float*)d_in[2];
  const float* pos = (const float*)d_in[3];
  const float* Wih0 = (const float*)d_in[4];
  const float* Whh0 = (const float*)d_in[5];
  const float* bih0 = (const float*)d_in[6];
  const float* bhh0 = (const float*)d_in[7];
  const float* Wih1 = (const float*)d_in[8];
  const float* Whh1 = (const float*)d_in[9];
  const float* bih1 = (const float*)d_in[10];
  const float* bhh1 = (const float*)d_in[11];
  const float* Wout = (const float*)d_in[12];
  const float* bout = (const float*)d_in[13];
  float* out = (float*)d_out;

  char* w = (char*)d_ws;
  auto alloc = [&](size_t bytes) {
    char* p = w;
    w += (bytes + 255) & ~(size_t)255;
    return p;
  };
  // zeroed region: flags + hs_all + h0 ping-pong
  unsigned int* flags = (unsigned int*)alloc(NBLK * 4);
  unsigned short* hs_all = (unsigned short*)alloc((size_t)4160 * HH * 2);  // 130 slots
  unsigned short* h0buf = (unsigned short*)alloc((size_t)2 * BH * 2);
  const size_t zero_bytes = (size_t)(w - (char*)d_ws);

  unsigned short* Xb = (unsigned short*)alloc((size_t)MPAD * EE * 2);
  unsigned short* Wih0b = (unsigned short*)alloc((size_t)FH * EE * 2);
  unsigned short* Woutb = (unsigned short*)alloc((size_t)VV * HH * 2);
  float* G0pre = (float*)alloc((size_t)MROWS * FH * 4);

  // 1) zero state buffers (incl. barrier flags) — every call
  hipLaunchKernelGGL(zero_k, dim3(2048), dim3(256), 0, stream, (uint4*)d_ws,
                     (int)(zero_bytes / 16));
  // 2) convert Wih0 / Wout to bf16
  hipLaunchKernelGGL(cvt_bf16_v4, dim3(1024), dim3(256), 0, stream, (const float4*)Wih0,
                     (u16x4*)Wih0b, FH * EE / 4);
  hipLaunchKernelGGL(cvt_bf16_v4, dim3(4096), dim3(256), 0, stream, (const float4*)Wout,
                     (u16x4*)Woutb, VV * HH / 4);
  // 3) embeddings + pos -> X
  hipLaunchKernelGGL(embed_k, dim3(MPAD), dim3(256), 0, stream, captions, etab, pos, Xb);
  // 4) G0pre = X @ Wih0^T + bih0 + bhh0
  hipLaunchKernelGGL(gemm_bt, dim3(32, 32), dim3(256), 0, stream, Xb, Wih0b, EE, FH, 0, bih0,
                     bhh0, G0pre);
  // 5) persistent recurrence (one launch, 128 phases, flag barrier)
  hipLaunchKernelGGL(lstm_persist, dim3(NBLK), dim3(256), 0, stream, Whh0, Wih1, Whh1, G0pre,
                     bih1, bhh1, h0buf, hs_all, flags);
  // 6) projection: logits = hs @ Wout^T + bout
  hipLaunchKernelGGL(gemm_bt, dim3(32, 250), dim3(256), 0, stream, hs_all + (size_t)BH, Woutb,
                     HH, VV, 1, bout, nullptr, out);
  // 7) out[:, 0, :] = 0
  hipLaunchKernelGGL(zero_out_t0, dim3(125, 32), dim3(256), 0, stream, out);
}

// Round 4
// 2547.777 us; speedup vs baseline: 1.2630x; 1.2630x over previous
//
#include <hip/hip_runtime.h>
#include <hip/hip_bf16.h>
#include <math.h>

typedef __attribute__((ext_vector_type(4))) float f32x4;
typedef __attribute__((ext_vector_type(8))) short s16x8;
typedef __attribute__((ext_vector_type(4))) unsigned short u16x4;
typedef __attribute__((ext_vector_type(4))) unsigned int u32x4;

#define MFMA16(a, b, c) __builtin_amdgcn_mfma_f32_16x16x32_bf16(a, b, c, 0, 0, 0)

static constexpr int BB = 32, TT = 128, EE = 512, HH = 1024, VV = 32000;
static constexpr int FH = 4 * HH;           // 4096 gate rows
static constexpr int MROWS = (TT - 1) * BB; // 4064 valid rows
static constexpr int MPAD = 4096;
static constexpr int BH = BB * HH;          // 32768
static constexpr int NBLK = 256;            // persistent grid

__device__ __forceinline__ unsigned short f2bf(float f) {
  unsigned int u = __float_as_uint(f);
  u = (u + 0x7FFFu + ((u >> 16) & 1u)) >> 16;
  return (unsigned short)u;
}
__device__ __forceinline__ float sigf(float x) { return 1.f / (1.f + __expf(-x)); }

__device__ __forceinline__ s16x8 pack8f(const float* p) {
  float4 x = *(const float4*)p;
  float4 y = *(const float4*)(p + 4);
  s16x8 r;
  r[0] = (short)f2bf(x.x); r[1] = (short)f2bf(x.y);
  r[2] = (short)f2bf(x.z); r[3] = (short)f2bf(x.w);
  r[4] = (short)f2bf(y.x); r[5] = (short)f2bf(y.y);
  r[6] = (short)f2bf(y.z); r[7] = (short)f2bf(y.w);
  return r;
}

// Coherent (sc0 sc1) 16B load: volatile forces L1/L2 bypass on gfx950,
// reading the device coherence point — no buffer_inv needed.
__device__ __forceinline__ s16x8 vload16(const unsigned short* p) {
  u32x4 v = *(const volatile u32x4*)p;
  return __builtin_bit_cast(s16x8, v);
}

__device__ __forceinline__ void gl_lds16(const void* g, void* l) {
  __builtin_amdgcn_global_load_lds(
      (const __attribute__((address_space(1))) unsigned int*)g,
      (__attribute__((address_space(3))) unsigned int*)l, 16, 0, 0);
}

// ---------------- zero / convert / embed ----------------

__global__ void zero_k(uint4* __restrict__ p, int n16) {
  int i = blockIdx.x * blockDim.x + threadIdx.x;
  int stride = gridDim.x * blockDim.x;
  uint4 z = {0u, 0u, 0u, 0u};
  for (; i < n16; i += stride) p[i] = z;
}

__global__ void cvt_bf16_v4(const float4* __restrict__ in, u16x4* __restrict__ out, int n4) {
  int i = blockIdx.x * blockDim.x + threadIdx.x;
  int stride = gridDim.x * blockDim.x;
  for (; i < n4; i += stride) {
    float4 v = in[i];
    u16x4 o;
    o[0] = f2bf(v.x); o[1] = f2bf(v.y); o[2] = f2bf(v.z); o[3] = f2bf(v.w);
    out[i] = o;
  }
}

__global__ __launch_bounds__(256) void embed_k(const int* __restrict__ captions,
                                               const float* __restrict__ etab,
                                               const float* __restrict__ pos,
                                               unsigned short* __restrict__ X) {
  const int m = blockIdx.x;  // row = t*32 + b
  const int t = m >> 5, b = m & 31;
  if (t < TT - 1) {
    const int tok = captions[b * TT + t];
    const float* er = etab + (size_t)tok * EE;
    for (int e = threadIdx.x; e < EE; e += 256)
      X[(size_t)m * EE + e] = f2bf(er[e] + pos[e]);
  } else {
    for (int e = threadIdx.x; e < EE; e += 256) X[(size_t)m * EE + e] = 0;
  }
}

__global__ void zero_out_t0(float* __restrict__ out) {
  out[(size_t)blockIdx.y * TT * VV + blockIdx.x * 256 + threadIdx.x] = 0.f;
}

// ---------------- C = A @ B^T bf16 MFMA GEMM, m97-style staging ----------------

__global__ __launch_bounds__(256) void gemm_bt(const unsigned short* __restrict__ A,
                                               const unsigned short* __restrict__ Bm,
                                               int K, int N, int mode,
                                               const float* __restrict__ bias0,
                                               const float* __restrict__ bias1,
                                               float* __restrict__ Cout) {
  __shared__ unsigned short As[128 * 64];
  __shared__ unsigned short Bs[128 * 64];
  const int tid = threadIdx.x;
  const int lane = tid & 63, wave = tid >> 6;
  const int wm = wave & 1, wn = wave >> 1;
  const int m0 = blockIdx.x * 128, n0 = blockIdx.y * 128;
  const int sch = (lane & 7) * 8;
  const int srbase = wave * 32 + (lane >> 3);
  f32x4 acc[4][4] = {};

  for (int k0 = 0; k0 < K; k0 += 64) {
    __syncthreads();
#pragma unroll
    for (int i = 0; i < 4; ++i) {
      const int r = srbase + i * 8;
      gl_lds16(&A[(size_t)(m0 + r) * K + k0 + sch], &As[(wave * 4 + i) * 512]);
      gl_lds16(&Bm[(size_t)(n0 + r) * K + k0 + sch], &Bs[(wave * 4 + i) * 512]);
    }
    __syncthreads();
#pragma unroll
    for (int kk = 0; kk < 64; kk += 32) {
      s16x8 af[4], bf[4];
#pragma unroll
      for (int f = 0; f < 4; ++f) {
        af[f] = *(const s16x8*)(&As[(wm * 64 + f * 16 + (lane & 15)) * 64 + kk + (lane >> 4) * 8]);
        bf[f] = *(const s16x8*)(&Bs[(wn * 64 + f * 16 + (lane & 15)) * 64 + kk + (lane >> 4) * 8]);
      }
#pragma unroll
      for (int mi = 0; mi < 4; ++mi)
#pragma unroll
        for (int ni = 0; ni < 4; ++ni)
          acc[mi][ni] = MFMA16(af[mi], bf[ni], acc[mi][ni]);
    }
  }

#pragma unroll
  for (int mi = 0; mi < 4; ++mi) {
#pragma unroll
    for (int ni = 0; ni < 4; ++ni) {
      const int col = n0 + wn * 64 + ni * 16 + (lane & 15);
      float bs = bias0[col] + (bias1 ? bias1[col] : 0.f);
      const int mbase = m0 + wm * 64 + mi * 16 + (lane >> 4) * 4;
#pragma unroll
      for (int r = 0; r < 4; ++r) {
        int m = mbase + r;
        if (m < MROWS) {
          float v = acc[mi][ni][r] + bs;
          if (mode == 0) {
            Cout[(size_t)m * N + col] = v;
          } else {
            int t = m >> 5, b = m & 31;
            Cout[((size_t)b * TT + (t + 1)) * VV + col] = v;
          }
        }
      }
    }
  }
}

// ---------------- persistent 2-layer LSTM, weights in registers ----------------
// NO agent fences / NO buffer_wbl2 / NO buffer_inv in the loop. Cross-block h
// data moves via sc0+sc1 (volatile) write-through stores and bypass loads; the
// barrier is: syncthreads (drains vmcnt) -> relaxed sc1 flag store -> relaxed
// sc1 flag poll -> syncthreads.

__device__ __forceinline__ void flagbar(unsigned int* __restrict__ flags, unsigned int target) {
  __syncthreads();  // compiler drains vmcnt(0) before s_barrier -> h stores at IC
  asm volatile("s_waitcnt vmcnt(0)" ::: "memory");
  if (threadIdx.x == 0)
    __hip_atomic_store(&flags[blockIdx.x], target, __ATOMIC_RELAXED, __HIP_MEMORY_SCOPE_AGENT);
  if (threadIdx.x < 64) {
    const int base = (int)threadIdx.x * 4;
    for (;;) {
      unsigned m0 = __hip_atomic_load(&flags[base + 0], __ATOMIC_RELAXED, __HIP_MEMORY_SCOPE_AGENT);
      unsigned m1 = __hip_atomic_load(&flags[base + 1], __ATOMIC_RELAXED, __HIP_MEMORY_SCOPE_AGENT);
      unsigned m2 = __hip_atomic_load(&flags[base + 2], __ATOMIC_RELAXED, __HIP_MEMORY_SCOPE_AGENT);
      unsigned m3 = __hip_atomic_load(&flags[base + 3], __ATOMIC_RELAXED, __HIP_MEMORY_SCOPE_AGENT);
      unsigned mn = min(min(m0, m1), min(m2, m3));
      if (__all(mn >= target)) break;
      __builtin_amdgcn_s_sleep(2);
    }
  }
  __syncthreads();
}

__global__ __launch_bounds__(256, 1) void lstm_persist(
    const float* __restrict__ Whh0f, const float* __restrict__ Wih1f,
    const float* __restrict__ Whh1f, const float* __restrict__ G0pre,
    const float* __restrict__ bih1, const float* __restrict__ bhh1,
    unsigned short* __restrict__ h0buf, unsigned short* __restrict__ hs_all,
    unsigned int* __restrict__ flags) {
  __shared__ float parts[4][2][2][16][16];  // [wave][ah][fi][row16][col16] 8KB
  const int bid = blockIdx.x;
  const int layer = bid >> 7;     // 0:L0 1:L1
  const int blk = bid & 127;
  const int tid = threadIdx.x, lane = tid & 63, wave = tid >> 6;
  const int jb = blk * 8;
  const int colIdx = lane & 15;
  const int kq = lane >> 4;                                 // 0..3
  const int wrow0 = (colIdx >> 3) * HH + jb + (colIdx & 7); // + fi*2*HH -> W row

  const int cb = tid >> 3, cjj = tid & 7;
  float creg = 0.f;
  float bsum[4];
  if (layer == 1) {
#pragma unroll
    for (int gi = 0; gi < 4; ++gi)
      bsum[gi] = bih1[gi * HH + jb + cjj] + bhh1[gi * HH + jb + cjj];
  }

  // ---- preload weights into registers (fp32 -> bf16), plain cached loads ----
  s16x8 wreg[16][2];
  const int kb = (layer == 0) ? wave * 256 : (wave & 1) * 512;
  if (layer == 0) {
#pragma unroll
    for (int fi = 0; fi < 2; ++fi) {
      const float* wp = Whh0f + (size_t)(wrow0 + fi * 2 * HH) * HH + kb + kq * 8;
#pragma unroll
      for (int ks = 0; ks < 8; ++ks) wreg[ks][fi] = pack8f(wp + ks * 32);
    }
  } else {
    const float* Wsrc = (wave < 2) ? Wih1f : Whh1f;
#pragma unroll
    for (int fi = 0; fi < 2; ++fi) {
      const float* wp = Wsrc + (size_t)(wrow0 + fi * 2 * HH) * HH + kb + kq * 8;
#pragma unroll
      for (int ks = 0; ks < 16; ++ks) wreg[ks][fi] = pack8f(wp + ks * 32);
    }
  }

  for (int t = 0; t < TT; ++t) {
    if (layer == 0) {
      if (t < TT - 1) {
        float gpre[4];
#pragma unroll
        for (int gi = 0; gi < 4; ++gi)
          gpre[gi] = G0pre[((size_t)t * BB + cb) * FH + gi * HH + jb + cjj];

        const unsigned short* h0read = h0buf + (size_t)(t & 1) * BH;
        const unsigned short* a0 = h0read + (size_t)(lane & 15) * HH + kb + kq * 8;
        const unsigned short* a1 = a0 + 16 * HH;
        // issue all coherent loads first, then MFMA (pipelined sc1 loads)
        s16x8 av0[8], av1[8];
#pragma unroll
        for (int ks = 0; ks < 8; ++ks) {
          av0[ks] = vload16(a0 + ks * 32);
          av1[ks] = vload16(a1 + ks * 32);
        }
        f32x4 acc00 = {}, acc01 = {}, acc10 = {}, acc11 = {};
#pragma unroll
        for (int ks = 0; ks < 8; ++ks) {
          acc00 = MFMA16(av0[ks], wreg[ks][0], acc00);
          acc01 = MFMA16(av0[ks], wreg[ks][1], acc01);
          acc10 = MFMA16(av1[ks], wreg[ks][0], acc10);
          acc11 = MFMA16(av1[ks], wreg[ks][1], acc11);
        }
#pragma unroll
        for (int r = 0; r < 4; ++r) {
          parts[wave][0][0][kq * 4 + r][colIdx] = acc00[r];
          parts[wave][0][1][kq * 4 + r][colIdx] = acc01[r];
          parts[wave][1][0][kq * 4 + r][colIdx] = acc10[r];
          parts[wave][1][1][kq * 4 + r][colIdx] = acc11[r];
        }
        __syncthreads();
        float g[4];
#pragma unroll
        for (int gi = 0; gi < 4; ++gi) {
          float s = gpre[gi];
          const int fi = gi >> 1, c = (gi & 1) * 8 + cjj;
#pragma unroll
          for (int w4 = 0; w4 < 4; ++w4) s += parts[w4][cb >> 4][fi][cb & 15][c];
          g[gi] = s;
        }
        const float i_ = sigf(g[0]), f_ = sigf(g[1]), gg = tanhf(g[2]), o_ = sigf(g[3]);
        creg = f_ * creg + i_ * gg;
        // coherent write-through store (sc0 sc1): visible at IC, no wbl2 needed
        *(volatile unsigned short*)&h0buf[(size_t)((t + 1) & 1) * BH +
                                          (size_t)cb * HH + jb + cjj] =
            f2bf(o_ * tanhf(creg));
      }
    } else {
      if (t >= 1) {
        const unsigned short* h0read = h0buf + (size_t)(t & 1) * BH;
        const unsigned short* Arow =
            (wave < 2) ? h0read : (hs_all + (size_t)(t - 1) * BH);
        const unsigned short* a0 = Arow + (size_t)(lane & 15) * HH + kb + kq * 8;
        const unsigned short* a1 = a0 + 16 * HH;
        s16x8 av0[16], av1[16];
#pragma unroll
        for (int ks = 0; ks < 16; ++ks) {
          av0[ks] = vload16(a0 + ks * 32);
          av1[ks] = vload16(a1 + ks * 32);
        }
        f32x4 acc00 = {}, acc01 = {}, acc10 = {}, acc11 = {};
#pragma unroll
        for (int ks = 0; ks < 16; ++ks) {
          acc00 = MFMA16(av0[ks], wreg[ks][0], acc00);
          acc01 = MFMA16(av0[ks], wreg[ks][1], acc01);
          acc10 = MFMA16(av1[ks], wreg[ks][0], acc10);
          acc11 = MFMA16(av1[ks], wreg[ks][1], acc11);
        }
#pragma unroll
        for (int r = 0; r < 4; ++r) {
          parts[wave][0][0][kq * 4 + r][colIdx] = acc00[r];
          parts[wave][0][1][kq * 4 + r][colIdx] = acc01[r];
          parts[wave][1][0][kq * 4 + r][colIdx] = acc10[r];
          parts[wave][1][1][kq * 4 + r][colIdx] = acc11[r];
        }
        __syncthreads();
        float g[4];
#pragma unroll
        for (int gi = 0; gi < 4; ++gi) {
          float s = bsum[gi];
          const int fi = gi >> 1, c = (gi & 1) * 8 + cjj;
#pragma unroll
          for (int w4 = 0; w4 < 4; ++w4) s += parts[w4][cb >> 4][fi][cb & 15][c];
          g[gi] = s;
        }
        const float i_ = sigf(g[0]), f_ = sigf(g[1]), gg = tanhf(g[2]), o_ = sigf(g[3]);
        creg = f_ * creg + i_ * gg;
        *(volatile unsigned short*)&hs_all[(size_t)t * BH + (size_t)cb * HH + jb + cjj] =
            f2bf(o_ * tanhf(creg));
      }
    }
    if (t < TT - 1) flagbar(flags, (unsigned int)(t + 1));
  }
}

// ---------------- host ----------------

extern "C" void kernel_launch(void* const* d_in, const int* in_sizes, int n_in,
                              void* d_out, int out_size, void* d_ws, size_t ws_size,
                              hipStream_t stream) {
  const int* captions = (const int*)d_in[1];
  const float* etab = (const float*)d_in[2];
  const float* pos = (const float*)d_in[3];
  const float* Wih0 = (const float*)d_in[4];
  const float* Whh0 = (const float*)d_in[5];
  const float* bih0 = (const float*)d_in[6];
  const float* bhh0 = (const float*)d_in[7];
  const float* Wih1 = (const float*)d_in[8];
  const float* Whh1 = (const float*)d_in[9];
  const float* bih1 = (const float*)d_in[10];
  const float* bhh1 = (const float*)d_in[11];
  const float* Wout = (const float*)d_in[12];
  const float* bout = (const float*)d_in[13];
  float* out = (float*)d_out;

  char* w = (char*)d_ws;
  auto alloc = [&](size_t bytes) {
    char* p = w;
    w += (bytes + 255) & ~(size_t)255;
    return p;
  };
  // zeroed region: flags + hs_all + h0 ping-pong
  unsigned int* flags = (unsigned int*)alloc(NBLK * 4);
  unsigned short* hs_all = (unsigned short*)alloc((size_t)4160 * HH * 2);  // 130 slots
  unsigned short* h0buf = (unsigned short*)alloc((size_t)2 * BH * 2);
  const size_t zero_bytes = (size_t)(w - (char*)d_ws);

  unsigned short* Xb = (unsigned short*)alloc((size_t)MPAD * EE * 2);
  unsigned short* Wih0b = (unsigned short*)alloc((size_t)FH * EE * 2);
  unsigned short* Woutb = (unsigned short*)alloc((size_t)VV * HH * 2);
  float* G0pre = (float*)alloc((size_t)MROWS * FH * 4);

  // 1) zero state buffers (incl. barrier flags) — every call
  hipLaunchKernelGGL(zero_k, dim3(2048), dim3(256), 0, stream, (uint4*)d_ws,
                     (int)(zero_bytes / 16));
  // 2) convert Wih0 / Wout to bf16
  hipLaunchKernelGGL(cvt_bf16_v4, dim3(1024), dim3(256), 0, stream, (const float4*)Wih0,
                     (u16x4*)Wih0b, FH * EE / 4);
  hipLaunchKernelGGL(cvt_bf16_v4, dim3(4096), dim3(256), 0, stream, (const float4*)Wout,
                     (u16x4*)Woutb, VV * HH / 4);
  // 3) embeddings + pos -> X
  hipLaunchKernelGGL(embed_k, dim3(MPAD), dim3(256), 0, stream, captions, etab, pos, Xb);
  // 4) G0pre = X @ Wih0^T + bih0 + bhh0
  hipLaunchKernelGGL(gemm_bt, dim3(32, 32), dim3(256), 0, stream, Xb, Wih0b, EE, FH, 0, bih0,
                     bhh0, G0pre);
  // 5) persistent recurrence (one launch, 128 phases, fence-free flag barrier)
  hipLaunchKernelGGL(lstm_persist, dim3(NBLK), dim3(256), 0, stream, Whh0, Wih1, Whh1, G0pre,
                     bih1, bhh1, h0buf, hs_all, flags);
  // 6) projection: logits = hs @ Wout^T + bout
  hipLaunchKernelGGL(gemm_bt, dim3(32, 250), dim3(256), 0, stream, hs_all + (size_t)BH, Woutb,
                     HH, VV, 1, bout, nullptr, out);
  // 7) out[:, 0, :] = 0
  hipLaunchKernelGGL(zero_out_t0, dim3(125, 32), dim3(256), 0, stream, out);
}

// Round 5
// 1613.331 us; speedup vs baseline: 1.9945x; 1.5792x over previous
//
#include <hip/hip_runtime.h>
#include <hip/hip_bf16.h>
#include <math.h>

typedef __attribute__((ext_vector_type(4))) float f32x4;
typedef __attribute__((ext_vector_type(8))) short s16x8;
typedef __attribute__((ext_vector_type(4))) unsigned short u16x4;
typedef __attribute__((ext_vector_type(4))) unsigned int u32x4;

#define MFMA16(a, b, c) __builtin_amdgcn_mfma_f32_16x16x32_bf16(a, b, c, 0, 0, 0)

static constexpr int BB = 32, TT = 128, EE = 512, HH = 1024, VV = 32000;
static constexpr int FH = 4 * HH;           // 4096 gate rows
static constexpr int MROWS = (TT - 1) * BB; // 4064 valid rows
static constexpr int MPAD = 4096;
static constexpr int BH = BB * HH;          // 32768
static constexpr int NBLK = 256;            // persistent grid

__device__ __forceinline__ unsigned short f2bf(float f) {
  unsigned int u = __float_as_uint(f);
  u = (u + 0x7FFFu + ((u >> 16) & 1u)) >> 16;
  return (unsigned short)u;
}
__device__ __forceinline__ float sigf(float x) { return 1.f / (1.f + __expf(-x)); }

__device__ __forceinline__ s16x8 pack8f(const float* p) {
  float4 x = *(const float4*)p;
  float4 y = *(const float4*)(p + 4);
  s16x8 r;
  r[0] = (short)f2bf(x.x); r[1] = (short)f2bf(x.y);
  r[2] = (short)f2bf(x.z); r[3] = (short)f2bf(x.w);
  r[4] = (short)f2bf(y.x); r[5] = (short)f2bf(y.y);
  r[6] = (short)f2bf(y.z); r[7] = (short)f2bf(y.w);
  return r;
}

__device__ __forceinline__ void gl_lds16(const void* g, void* l) {
  __builtin_amdgcn_global_load_lds(
      (const __attribute__((address_space(1))) unsigned int*)g,
      (__attribute__((address_space(3))) unsigned int*)l, 16, 0, 0);
}

// ---------------- zero / convert / embed ----------------

__global__ void zero_k(uint4* __restrict__ p, int n16) {
  int i = blockIdx.x * blockDim.x + threadIdx.x;
  int stride = gridDim.x * blockDim.x;
  uint4 z = {0u, 0u, 0u, 0u};
  for (; i < n16; i += stride) p[i] = z;
}

__global__ void cvt_bf16_v4(const float4* __restrict__ in, u16x4* __restrict__ out, int n4) {
  int i = blockIdx.x * blockDim.x + threadIdx.x;
  int stride = gridDim.x * blockDim.x;
  for (; i < n4; i += stride) {
    float4 v = in[i];
    u16x4 o;
    o[0] = f2bf(v.x); o[1] = f2bf(v.y); o[2] = f2bf(v.z); o[3] = f2bf(v.w);
    out[i] = o;
  }
}

__global__ __launch_bounds__(256) void embed_k(const int* __restrict__ captions,
                                               const float* __restrict__ etab,
                                               const float* __restrict__ pos,
                                               unsigned short* __restrict__ X) {
  const int m = blockIdx.x;  // row = t*32 + b
  const int t = m >> 5, b = m & 31;
  if (t < TT - 1) {
    const int tok = captions[b * TT + t];
    const float* er = etab + (size_t)tok * EE;
    for (int e = threadIdx.x; e < EE; e += 256)
      X[(size_t)m * EE + e] = f2bf(er[e] + pos[e]);
  } else {
    for (int e = threadIdx.x; e < EE; e += 256) X[(size_t)m * EE + e] = 0;
  }
}

__global__ void zero_out_t0(float* __restrict__ out) {
  out[(size_t)blockIdx.y * TT * VV + blockIdx.x * 256 + threadIdx.x] = 0.f;
}

// ---------------- C = A @ B^T bf16 MFMA GEMM, m97-style staging ----------------

__global__ __launch_bounds__(256) void gemm_bt(const unsigned short* __restrict__ A,
                                               const unsigned short* __restrict__ Bm,
                                               int K, int N, int mode,
                                               const float* __restrict__ bias0,
                                               const float* __restrict__ bias1,
                                               float* __restrict__ Cout) {
  __shared__ unsigned short As[128 * 64];
  __shared__ unsigned short Bs[128 * 64];
  const int tid = threadIdx.x;
  const int lane = tid & 63, wave = tid >> 6;
  const int wm = wave & 1, wn = wave >> 1;
  const int m0 = blockIdx.x * 128, n0 = blockIdx.y * 128;
  const int sch = (lane & 7) * 8;
  const int srbase = wave * 32 + (lane >> 3);
  f32x4 acc[4][4] = {};

  for (int k0 = 0; k0 < K; k0 += 64) {
    __syncthreads();
#pragma unroll
    for (int i = 0; i < 4; ++i) {
      const int r = srbase + i * 8;
      gl_lds16(&A[(size_t)(m0 + r) * K + k0 + sch], &As[(wave * 4 + i) * 512]);
      gl_lds16(&Bm[(size_t)(n0 + r) * K + k0 + sch], &Bs[(wave * 4 + i) * 512]);
    }
    __syncthreads();
#pragma unroll
    for (int kk = 0; kk < 64; kk += 32) {
      s16x8 af[4], bf[4];
#pragma unroll
      for (int f = 0; f < 4; ++f) {
        af[f] = *(const s16x8*)(&As[(wm * 64 + f * 16 + (lane & 15)) * 64 + kk + (lane >> 4) * 8]);
        bf[f] = *(const s16x8*)(&Bs[(wn * 64 + f * 16 + (lane & 15)) * 64 + kk + (lane >> 4) * 8]);
      }
#pragma unroll
      for (int mi = 0; mi < 4; ++mi)
#pragma unroll
        for (int ni = 0; ni < 4; ++ni)
          acc[mi][ni] = MFMA16(af[mi], bf[ni], acc[mi][ni]);
    }
  }

#pragma unroll
  for (int mi = 0; mi < 4; ++mi) {
#pragma unroll
    for (int ni = 0; ni < 4; ++ni) {
      const int col = n0 + wn * 64 + ni * 16 + (lane & 15);
      float bs = bias0[col] + (bias1 ? bias1[col] : 0.f);
      const int mbase = m0 + wm * 64 + mi * 16 + (lane >> 4) * 4;
#pragma unroll
      for (int r = 0; r < 4; ++r) {
        int m = mbase + r;
        if (m < MROWS) {
          float v = acc[mi][ni][r] + bs;
          if (mode == 0) {
            Cout[(size_t)m * N + col] = v;
          } else {
            int t = m >> 5, b = m & 31;
            Cout[((size_t)b * TT + (t + 1)) * VV + col] = v;
          }
        }
      }
    }
  }
}

// ---------------- persistent 2-layer LSTM, weights in registers ----------------
// h-state: write-once sequential slots (h0seq[t], hs_all[t]) -> consumers use
// PLAIN CACHED loads (L2 broadcast amplification; a slot address is never
// rewritten within a call, so no stale-line hazard). Producers store volatile
// (sc0 sc1 write-through to IC). Barrier: per-block arrival flag (sc1 store),
// block 0 aggregates and broadcasts an epoch word replicated over 8 cache
// lines; members poll one replica with s_sleep throttling. No RMW, no fences.

__device__ __forceinline__ void flagbar2(unsigned int* __restrict__ flags,
                                         unsigned int* __restrict__ epoch,
                                         unsigned int target) {
  asm volatile("s_waitcnt vmcnt(0)" ::: "memory");  // this wave's h-stores at IC
  __syncthreads();                                  // all waves drained + arrived
  const int tid = threadIdx.x;
  const int bid = blockIdx.x;
  if (tid == 0)
    *(volatile unsigned int*)&flags[bid] = target;  // arrival (sc0 sc1)
  if (bid == 0) {
    if (tid < 64) {
      for (;;) {
        u32x4 v = *(const volatile u32x4*)&flags[tid * 4];
        unsigned mn = min(min(v[0], v[1]), min(v[2], v[3]));
        if (__all(mn >= target)) break;
        __builtin_amdgcn_s_sleep(2);
      }
      if (tid < 8) *(volatile unsigned int*)&epoch[tid * 32] = target;
    }
  } else {
    if (tid == 0) {
      volatile unsigned int* ep = &epoch[(bid & 7) * 32];
      while (*ep < target) __builtin_amdgcn_s_sleep(4);
    }
  }
  __syncthreads();
  asm volatile("" ::: "memory");  // keep data loads below the poll
}

__global__ __launch_bounds__(256, 1) void lstm_persist(
    const float* __restrict__ Whh0f, const float* __restrict__ Wih1f,
    const float* __restrict__ Whh1f, const float* __restrict__ G0pre,
    const float* __restrict__ bih1, const float* __restrict__ bhh1,
    unsigned short* __restrict__ h0seq, unsigned short* __restrict__ hs_all,
    unsigned int* __restrict__ flags, unsigned int* __restrict__ epoch) {
  __shared__ float parts[4][2][2][16][16];  // [wave][ah][fi][row16][col16] 8KB
  const int bid = blockIdx.x;
  const int layer = bid >> 7;     // 0:L0 1:L1
  const int blk = bid & 127;
  const int tid = threadIdx.x, lane = tid & 63, wave = tid >> 6;
  const int jb = blk * 8;
  const int colIdx = lane & 15;
  const int kq = lane >> 4;                                 // 0..3
  const int wrow0 = (colIdx >> 3) * HH + jb + (colIdx & 7); // + fi*2*HH -> W row

  const int cb = tid >> 3, cjj = tid & 7;
  float creg = 0.f;
  float bsum[4];
  if (layer == 1) {
#pragma unroll
    for (int gi = 0; gi < 4; ++gi)
      bsum[gi] = bih1[gi * HH + jb + cjj] + bhh1[gi * HH + jb + cjj];
  }

  // ---- preload weights into registers (fp32 -> bf16), plain cached loads ----
  s16x8 wreg[16][2];
  const int kb = (layer == 0) ? wave * 256 : (wave & 1) * 512;
  if (layer == 0) {
#pragma unroll
    for (int fi = 0; fi < 2; ++fi) {
      const float* wp = Whh0f + (size_t)(wrow0 + fi * 2 * HH) * HH + kb + kq * 8;
#pragma unroll
      for (int ks = 0; ks < 8; ++ks) wreg[ks][fi] = pack8f(wp + ks * 32);
    }
  } else {
    const float* Wsrc = (wave < 2) ? Wih1f : Whh1f;
#pragma unroll
    for (int fi = 0; fi < 2; ++fi) {
      const float* wp = Wsrc + (size_t)(wrow0 + fi * 2 * HH) * HH + kb + kq * 8;
#pragma unroll
      for (int ks = 0; ks < 16; ++ks) wreg[ks][fi] = pack8f(wp + ks * 32);
    }
  }

  for (int t = 0; t < TT; ++t) {
    if (layer == 0) {
      if (t < TT - 1) {
        float gpre[4];
#pragma unroll
        for (int gi = 0; gi < 4; ++gi)
          gpre[gi] = G0pre[((size_t)t * BB + cb) * FH + gi * HH + jb + cjj];

        // h0seq[t] = h0(t-1): fresh address, written last phase -> cached load
        const unsigned short* a0 =
            h0seq + (size_t)t * BH + (size_t)(lane & 15) * HH + kb + kq * 8;
        const unsigned short* a1 = a0 + 16 * HH;
        f32x4 acc00 = {}, acc01 = {}, acc10 = {}, acc11 = {};
#pragma unroll
        for (int ks = 0; ks < 8; ++ks) {
          s16x8 av0 = *(const s16x8*)(a0 + ks * 32);
          s16x8 av1 = *(const s16x8*)(a1 + ks * 32);
          acc00 = MFMA16(av0, wreg[ks][0], acc00);
          acc01 = MFMA16(av0, wreg[ks][1], acc01);
          acc10 = MFMA16(av1, wreg[ks][0], acc10);
          acc11 = MFMA16(av1, wreg[ks][1], acc11);
        }
#pragma unroll
        for (int r = 0; r < 4; ++r) {
          parts[wave][0][0][kq * 4 + r][colIdx] = acc00[r];
          parts[wave][0][1][kq * 4 + r][colIdx] = acc01[r];
          parts[wave][1][0][kq * 4 + r][colIdx] = acc10[r];
          parts[wave][1][1][kq * 4 + r][colIdx] = acc11[r];
        }
        __syncthreads();
        float g[4];
#pragma unroll
        for (int gi = 0; gi < 4; ++gi) {
          float s = gpre[gi];
          const int fi = gi >> 1, c = (gi & 1) * 8 + cjj;
#pragma unroll
          for (int w4 = 0; w4 < 4; ++w4) s += parts[w4][cb >> 4][fi][cb & 15][c];
          g[gi] = s;
        }
        const float i_ = sigf(g[0]), f_ = sigf(g[1]), gg = tanhf(g[2]), o_ = sigf(g[3]);
        creg = f_ * creg + i_ * gg;
        // write-through coherent store -> IC (fresh slot t+1)
        *(volatile unsigned short*)&h0seq[(size_t)(t + 1) * BH +
                                          (size_t)cb * HH + jb + cjj] =
            f2bf(o_ * tanhf(creg));
      }
    } else {
      if (t >= 1) {
        const unsigned short* Arow = (wave < 2)
                                         ? (h0seq + (size_t)t * BH)           // h0(t-1)
                                         : (hs_all + (size_t)(t - 1) * BH);   // h1(t-2)
        const unsigned short* a0 = Arow + (size_t)(lane & 15) * HH + kb + kq * 8;
        const unsigned short* a1 = a0 + 16 * HH;
        f32x4 acc00 = {}, acc01 = {}, acc10 = {}, acc11 = {};
#pragma unroll
        for (int ks = 0; ks < 16; ++ks) {
          s16x8 av0 = *(const s16x8*)(a0 + ks * 32);
          s16x8 av1 = *(const s16x8*)(a1 + ks * 32);
          acc00 = MFMA16(av0, wreg[ks][0], acc00);
          acc01 = MFMA16(av0, wreg[ks][1], acc01);
          acc10 = MFMA16(av1, wreg[ks][0], acc10);
          acc11 = MFMA16(av1, wreg[ks][1], acc11);
        }
#pragma unroll
        for (int r = 0; r < 4; ++r) {
          parts[wave][0][0][kq * 4 + r][colIdx] = acc00[r];
          parts[wave][0][1][kq * 4 + r][colIdx] = acc01[r];
          parts[wave][1][0][kq * 4 + r][colIdx] = acc10[r];
          parts[wave][1][1][kq * 4 + r][colIdx] = acc11[r];
        }
        __syncthreads();
        float g[4];
#pragma unroll
        for (int gi = 0; gi < 4; ++gi) {
          float s = bsum[gi];
          const int fi = gi >> 1, c = (gi & 1) * 8 + cjj;
#pragma unroll
          for (int w4 = 0; w4 < 4; ++w4) s += parts[w4][cb >> 4][fi][cb & 15][c];
          g[gi] = s;
        }
        const float i_ = sigf(g[0]), f_ = sigf(g[1]), gg = tanhf(g[2]), o_ = sigf(g[3]);
        creg = f_ * creg + i_ * gg;
        *(volatile unsigned short*)&hs_all[(size_t)t * BH + (size_t)cb * HH + jb + cjj] =
            f2bf(o_ * tanhf(creg));
      }
    }
    if (t < TT - 1) flagbar2(flags, epoch, (unsigned int)(t + 1));
  }
}

// ---------------- host ----------------

extern "C" void kernel_launch(void* const* d_in, const int* in_sizes, int n_in,
                              void* d_out, int out_size, void* d_ws, size_t ws_size,
                              hipStream_t stream) {
  const int* captions = (const int*)d_in[1];
  const float* etab = (const float*)d_in[2];
  const float* pos = (const float*)d_in[3];
  const float* Wih0 = (const float*)d_in[4];
  const float* Whh0 = (const float*)d_in[5];
  const float* bih0 = (const float*)d_in[6];
  const float* bhh0 = (const float*)d_in[7];
  const float* Wih1 = (const float*)d_in[8];
  const float* Whh1 = (const float*)d_in[9];
  const float* bih1 = (const float*)d_in[10];
  const float* bhh1 = (const float*)d_in[11];
  const float* Wout = (const float*)d_in[12];
  const float* bout = (const float*)d_in[13];
  float* out = (float*)d_out;

  char* w = (char*)d_ws;
  auto alloc = [&](size_t bytes) {
    char* p = w;
    w += (bytes + 255) & ~(size_t)255;
    return p;
  };
  // layout: flags(1KB) epoch(1KB) h0seq(8MB) hs_all(8.5MB) ...
  unsigned int* flags = (unsigned int*)alloc(1024);
  unsigned int* epoch = (unsigned int*)alloc(1024);
  unsigned short* h0seq = (unsigned short*)alloc((size_t)TT * BH * 2);      // slots 0..127
  unsigned short* hs_all = (unsigned short*)alloc((size_t)4160 * HH * 2);   // 130 slots

  unsigned short* Xb = (unsigned short*)alloc((size_t)MPAD * EE * 2);
  unsigned short* Wih0b = (unsigned short*)alloc((size_t)FH * EE * 2);
  unsigned short* Woutb = (unsigned short*)alloc((size_t)VV * HH * 2);
  float* G0pre = (float*)alloc((size_t)MROWS * FH * 4);

  // 1) zero only what is read-before-written: flags+epoch+h0seq[0] (contiguous)
  //    and hs_all[0]
  hipLaunchKernelGGL(zero_k, dim3(17), dim3(256), 0, stream, (uint4*)flags,
                     (int)((1024 + 1024 + (size_t)BH * 2) / 16));
  hipLaunchKernelGGL(zero_k, dim3(16), dim3(256), 0, stream, (uint4*)hs_all,
                     (int)(((size_t)BH * 2) / 16));
  // 2) convert Wih0 / Wout to bf16
  hipLaunchKernelGGL(cvt_bf16_v4, dim3(1024), dim3(256), 0, stream, (const float4*)Wih0,
                     (u16x4*)Wih0b, FH * EE / 4);
  hipLaunchKernelGGL(cvt_bf16_v4, dim3(4096), dim3(256), 0, stream, (const float4*)Wout,
                     (u16x4*)Woutb, VV * HH / 4);
  // 3) embeddings + pos -> X
  hipLaunchKernelGGL(embed_k, dim3(MPAD), dim3(256), 0, stream, captions, etab, pos, Xb);
  // 4) G0pre = X @ Wih0^T + bih0 + bhh0
  hipLaunchKernelGGL(gemm_bt, dim3(32, 32), dim3(256), 0, stream, Xb, Wih0b, EE, FH, 0, bih0,
                     bhh0, G0pre);
  // 5) persistent recurrence (one launch, 128 phases, hierarchical flag barrier)
  hipLaunchKernelGGL(lstm_persist, dim3(NBLK), dim3(256), 0, stream, Whh0, Wih1, Whh1, G0pre,
                     bih1, bhh1, h0seq, hs_all, flags, epoch);
  // 6) projection: logits = hs @ Wout^T + bout
  hipLaunchKernelGGL(gemm_bt, dim3(32, 250), dim3(256), 0, stream, hs_all + (size_t)BH, Woutb,
                     HH, VV, 1, bout, nullptr, out);
  // 7) out[:, 0, :] = 0
  hipLaunchKernelGGL(zero_out_t0, dim3(125, 32), dim3(256), 0, stream, out);
}

// Round 6
// 1588.541 us; speedup vs baseline: 2.0256x; 1.0156x over previous
//
#include <hip/hip_runtime.h>
#include <hip/hip_bf16.h>
#include <math.h>

typedef __attribute__((ext_vector_type(4))) float f32x4;
typedef __attribute__((ext_vector_type(8))) short s16x8;
typedef __attribute__((ext_vector_type(4))) unsigned short u16x4;

#define MFMA16(a, b, c) __builtin_amdgcn_mfma_f32_16x16x32_bf16(a, b, c, 0, 0, 0)

static constexpr int BB = 32, TT = 128, EE = 512, HH = 1024, VV = 32000;
static constexpr int FH = 4 * HH;           // 4096 gate rows
static constexpr int MROWS = (TT - 1) * BB; // 4064 valid rows
static constexpr int MPAD = 4096;
static constexpr int BH = BB * HH;          // 32768
static constexpr int NBLK = 256;            // persistent grid

__device__ __forceinline__ unsigned short f2bf(float f) {
  unsigned int u = __float_as_uint(f);
  u = (u + 0x7FFFu + ((u >> 16) & 1u)) >> 16;
  return (unsigned short)u;
}
__device__ __forceinline__ float sigf(float x) { return 1.f / (1.f + __expf(-x)); }

__device__ __forceinline__ s16x8 pack8f(const float* p) {
  float4 x = *(const float4*)p;
  float4 y = *(const float4*)(p + 4);
  s16x8 r;
  r[0] = (short)f2bf(x.x); r[1] = (short)f2bf(x.y);
  r[2] = (short)f2bf(x.z); r[3] = (short)f2bf(x.w);
  r[4] = (short)f2bf(y.x); r[5] = (short)f2bf(y.y);
  r[6] = (short)f2bf(y.z); r[7] = (short)f2bf(y.w);
  return r;
}

__device__ __forceinline__ void gl_lds16(const void* g, void* l) {
  __builtin_amdgcn_global_load_lds(
      (const __attribute__((address_space(1))) unsigned int*)g,
      (__attribute__((address_space(3))) unsigned int*)l, 16, 0, 0);
}

// ---------------- zero / convert / embed ----------------

__global__ void zero_k(uint4* __restrict__ p, int n16) {
  int i = blockIdx.x * blockDim.x + threadIdx.x;
  int stride = gridDim.x * blockDim.x;
  uint4 z = {0u, 0u, 0u, 0u};
  for (; i < n16; i += stride) p[i] = z;
}

__global__ void cvt_bf16_v4(const float4* __restrict__ in, u16x4* __restrict__ out, int n4) {
  int i = blockIdx.x * blockDim.x + threadIdx.x;
  int stride = gridDim.x * blockDim.x;
  for (; i < n4; i += stride) {
    float4 v = in[i];
    u16x4 o;
    o[0] = f2bf(v.x); o[1] = f2bf(v.y); o[2] = f2bf(v.z); o[3] = f2bf(v.w);
    out[i] = o;
  }
}

__global__ __launch_bounds__(256) void embed_k(const int* __restrict__ captions,
                                               const float* __restrict__ etab,
                                               const float* __restrict__ pos,
                                               unsigned short* __restrict__ X) {
  const int m = blockIdx.x;  // row = t*32 + b
  const int t = m >> 5, b = m & 31;
  if (t < TT - 1) {
    const int tok = captions[b * TT + t];
    const float* er = etab + (size_t)tok * EE;
    for (int e = threadIdx.x; e < EE; e += 256)
      X[(size_t)m * EE + e] = f2bf(er[e] + pos[e]);
  } else {
    for (int e = threadIdx.x; e < EE; e += 256) X[(size_t)m * EE + e] = 0;
  }
}

__global__ void zero_out_t0(float* __restrict__ out) {
  out[(size_t)blockIdx.y * TT * VV + blockIdx.x * 256 + threadIdx.x] = 0.f;
}

// ---------------- C = A @ B^T bf16 MFMA GEMM, m97-style staging ----------------
// XCD-aware bijective swizzle (nwg % 8 == 0 for both call sites).

__global__ __launch_bounds__(256) void gemm_bt(const unsigned short* __restrict__ A,
                                               const unsigned short* __restrict__ Bm,
                                               int K, int N, int mode,
                                               const float* __restrict__ bias0,
                                               const float* __restrict__ bias1,
                                               float* __restrict__ Cout) {
  __shared__ unsigned short As[128 * 64];
  __shared__ unsigned short Bs[128 * 64];
  const int tid = threadIdx.x;
  const int lane = tid & 63, wave = tid >> 6;
  const int wm = wave & 1, wn = wave >> 1;
  const int nwg = gridDim.x * gridDim.y;
  const int lin = blockIdx.y * gridDim.x + blockIdx.x;
  const int cpx = nwg >> 3;
  const int wg = (lin & 7) * cpx + (lin >> 3);
  const int m0 = (wg % gridDim.x) * 128, n0 = (wg / gridDim.x) * 128;
  const int sch = (lane & 7) * 8;
  const int srbase = wave * 32 + (lane >> 3);
  f32x4 acc[4][4] = {};

  for (int k0 = 0; k0 < K; k0 += 64) {
    __syncthreads();
#pragma unroll
    for (int i = 0; i < 4; ++i) {
      const int r = srbase + i * 8;
      gl_lds16(&A[(size_t)(m0 + r) * K + k0 + sch], &As[(wave * 4 + i) * 512]);
      gl_lds16(&Bm[(size_t)(n0 + r) * K + k0 + sch], &Bs[(wave * 4 + i) * 512]);
    }
    __syncthreads();
#pragma unroll
    for (int kk = 0; kk < 64; kk += 32) {
      s16x8 af[4], bf[4];
#pragma unroll
      for (int f = 0; f < 4; ++f) {
        af[f] = *(const s16x8*)(&As[(wm * 64 + f * 16 + (lane & 15)) * 64 + kk + (lane >> 4) * 8]);
        bf[f] = *(const s16x8*)(&Bs[(wn * 64 + f * 16 + (lane & 15)) * 64 + kk + (lane >> 4) * 8]);
      }
#pragma unroll
      for (int mi = 0; mi < 4; ++mi)
#pragma unroll
        for (int ni = 0; ni < 4; ++ni)
          acc[mi][ni] = MFMA16(af[mi], bf[ni], acc[mi][ni]);
    }
  }

#pragma unroll
  for (int mi = 0; mi < 4; ++mi) {
#pragma unroll
    for (int ni = 0; ni < 4; ++ni) {
      const int col = n0 + wn * 64 + ni * 16 + (lane & 15);
      float bs = bias0[col] + (bias1 ? bias1[col] : 0.f);
      const int mbase = m0 + wm * 64 + mi * 16 + (lane >> 4) * 4;
#pragma unroll
      for (int r = 0; r < 4; ++r) {
        int m = mbase + r;
        if (m < MROWS) {
          float v = acc[mi][ni][r] + bs;
          if (mode == 0) {
            Cout[(size_t)m * N + col] = v;
          } else {
            int t = m >> 5, b = m & 31;
            Cout[((size_t)b * TT + (t + 1)) * VV + col] = v;
          }
        }
      }
    }
  }
}

// ---------------- persistent 2-layer LSTM, weights in registers ----------------
// Single-writer cache lines everywhere in the loop:
//  - arrival flags at 128B stride (one line per block)
//  - h-state block-major: h[slot][producer_blk][batch][8cols]; each producer's
//    phase output = contiguous 512B (4 lines), stores coalesce to line bursts.
// Producers store volatile (write-through to IC); consumers use plain cached
// loads of write-once addresses. h1 additionally stored row-major (plain, for
// the projection GEMM; never read in-loop).

__device__ __forceinline__ void flagbar3(unsigned int* __restrict__ flags,
                                         unsigned int* __restrict__ epoch,
                                         unsigned int target) {
  asm volatile("s_waitcnt vmcnt(0)" ::: "memory");  // this wave's h-stores at IC
  __syncthreads();                                  // all waves drained
  const int tid = threadIdx.x;
  const int bid = blockIdx.x;
  if (tid == 0)
    *(volatile unsigned int*)&flags[bid * 32] = target;  // own line
  if (bid == 0) {
    if (tid < 64) {
      for (;;) {
        unsigned a = __hip_atomic_load(&flags[(tid * 4 + 0) * 32], __ATOMIC_RELAXED,
                                       __HIP_MEMORY_SCOPE_AGENT);
        unsigned b = __hip_atomic_load(&flags[(tid * 4 + 1) * 32], __ATOMIC_RELAXED,
                                       __HIP_MEMORY_SCOPE_AGENT);
        unsigned c = __hip_atomic_load(&flags[(tid * 4 + 2) * 32], __ATOMIC_RELAXED,
                                       __HIP_MEMORY_SCOPE_AGENT);
        unsigned d = __hip_atomic_load(&flags[(tid * 4 + 3) * 32], __ATOMIC_RELAXED,
                                       __HIP_MEMORY_SCOPE_AGENT);
        unsigned mn = min(min(a, b), min(c, d));
        if (__all(mn >= target)) break;
        __builtin_amdgcn_s_sleep(1);
      }
      if (tid < 8) *(volatile unsigned int*)&epoch[tid * 32] = target;
    }
  } else if (tid == 0) {
    volatile unsigned int* ep = &epoch[(bid & 7) * 32];
    while (*ep < target) __builtin_amdgcn_s_sleep(2);
  }
  __syncthreads();
  asm volatile("" ::: "memory");
}

__global__ __launch_bounds__(256, 1) void lstm_persist(
    const float* __restrict__ Whh0f, const float* __restrict__ Wih1f,
    const float* __restrict__ Whh1f, const float* __restrict__ G0pre,
    const float* __restrict__ bih1, const float* __restrict__ bhh1,
    unsigned short* __restrict__ h0seq, unsigned short* __restrict__ hseq1,
    unsigned short* __restrict__ hs_all,
    unsigned int* __restrict__ flags, unsigned int* __restrict__ epoch) {
  __shared__ float parts[4][2][2][16][16];  // [wave][ah][fi][row16][col16] 8KB
  const int bid = blockIdx.x;
  const int layer = bid >> 7;     // 0:L0 1:L1
  const int blk = bid & 127;
  const int tid = threadIdx.x, lane = tid & 63, wave = tid >> 6;
  const int jb = blk * 8;
  const int colIdx = lane & 15;
  const int kq = lane >> 4;                                 // 0..3
  const int wrow0 = (colIdx >> 3) * HH + jb + (colIdx & 7); // + fi*2*HH -> W row

  const int cb = tid >> 3, cjj = tid & 7;
  float creg = 0.f;
  float bsum[4];
  if (layer == 1) {
#pragma unroll
    for (int gi = 0; gi < 4; ++gi)
      bsum[gi] = bih1[gi * HH + jb + cjj] + bhh1[gi * HH + jb + cjj];
  }

  // ---- preload weights into registers (fp32 -> bf16), plain cached loads ----
  s16x8 wreg[16][2];
  const int kb = (layer == 0) ? wave * 256 : (wave & 1) * 512;
  if (layer == 0) {
#pragma unroll
    for (int fi = 0; fi < 2; ++fi) {
      const float* wp = Whh0f + (size_t)(wrow0 + fi * 2 * HH) * HH + kb + kq * 8;
#pragma unroll
      for (int ks = 0; ks < 8; ++ks) wreg[ks][fi] = pack8f(wp + ks * 32);
    }
  } else {
    const float* Wsrc = (wave < 2) ? Wih1f : Whh1f;
#pragma unroll
    for (int fi = 0; fi < 2; ++fi) {
      const float* wp = Wsrc + (size_t)(wrow0 + fi * 2 * HH) * HH + kb + kq * 8;
#pragma unroll
      for (int ks = 0; ks < 16; ++ks) wreg[ks][fi] = pack8f(wp + ks * 32);
    }
  }

  // block-major fragment base: record(pb, b, c) at pb*256 + b*8 + c
  // k -> (pb = k>>3, c = k&7); 8 consecutive k (k%8==0) = one 16B record chunk
  const int frag_off = (kb >> 3) * 256 + kq * 256 + (lane & 15) * 8;  // pb=(kb>>3)+kq

  for (int t = 0; t < TT; ++t) {
    if (layer == 0) {
      if (t < TT - 1) {
        float gpre[4];
#pragma unroll
        for (int gi = 0; gi < 4; ++gi)
          gpre[gi] = G0pre[((size_t)t * BB + cb) * FH + gi * HH + jb + cjj];

        const unsigned short* a0 = h0seq + (size_t)t * BH + frag_off;
        const unsigned short* a1 = a0 + 128;  // batch rows +16
        f32x4 acc00 = {}, acc01 = {}, acc10 = {}, acc11 = {};
#pragma unroll
        for (int ks = 0; ks < 8; ++ks) {
          s16x8 av0 = *(const s16x8*)(a0 + ks * 1024);  // pb += 4 per chunk
          s16x8 av1 = *(const s16x8*)(a1 + ks * 1024);
          acc00 = MFMA16(av0, wreg[ks][0], acc00);
          acc01 = MFMA16(av0, wreg[ks][1], acc01);
          acc10 = MFMA16(av1, wreg[ks][0], acc10);
          acc11 = MFMA16(av1, wreg[ks][1], acc11);
        }
#pragma unroll
        for (int r = 0; r < 4; ++r) {
          parts[wave][0][0][kq * 4 + r][colIdx] = acc00[r];
          parts[wave][0][1][kq * 4 + r][colIdx] = acc01[r];
          parts[wave][1][0][kq * 4 + r][colIdx] = acc10[r];
          parts[wave][1][1][kq * 4 + r][colIdx] = acc11[r];
        }
        __syncthreads();
        float g[4];
#pragma unroll
        for (int gi = 0; gi < 4; ++gi) {
          float s = gpre[gi];
          const int fi = gi >> 1, c = (gi & 1) * 8 + cjj;
#pragma unroll
          for (int w4 = 0; w4 < 4; ++w4) s += parts[w4][cb >> 4][fi][cb & 15][c];
          g[gi] = s;
        }
        const float i_ = sigf(g[0]), f_ = sigf(g[1]), gg = tanhf(g[2]), o_ = sigf(g[3]);
        creg = f_ * creg + i_ * gg;
        // block-major write: contiguous 512B per block, single-writer lines
        *(volatile unsigned short*)&h0seq[(size_t)(t + 1) * BH + blk * 256 + tid] =
            f2bf(o_ * tanhf(creg));
      }
    } else {
      if (t >= 1) {
        const unsigned short* base = (wave < 2)
                                         ? (h0seq + (size_t)t * BH)         // h0(t-1)
                                         : (hseq1 + (size_t)(t - 1) * BH);  // h1(t-2)
        const unsigned short* a0 = base + frag_off;
        const unsigned short* a1 = a0 + 128;
        f32x4 acc00 = {}, acc01 = {}, acc10 = {}, acc11 = {};
#pragma unroll
        for (int ks = 0; ks < 16; ++ks) {
          s16x8 av0 = *(const s16x8*)(a0 + ks * 1024);
          s16x8 av1 = *(const s16x8*)(a1 + ks * 1024);
          acc00 = MFMA16(av0, wreg[ks][0], acc00);
          acc01 = MFMA16(av0, wreg[ks][1], acc01);
          acc10 = MFMA16(av1, wreg[ks][0], acc10);
          acc11 = MFMA16(av1, wreg[ks][1], acc11);
        }
#pragma unroll
        for (int r = 0; r < 4; ++r) {
          parts[wave][0][0][kq * 4 + r][colIdx] = acc00[r];
          parts[wave][0][1][kq * 4 + r][colIdx] = acc01[r];
          parts[wave][1][0][kq * 4 + r][colIdx] = acc10[r];
          parts[wave][1][1][kq * 4 + r][colIdx] = acc11[r];
        }
        __syncthreads();
        float g[4];
#pragma unroll
        for (int gi = 0; gi < 4; ++gi) {
          float s = bsum[gi];
          const int fi = gi >> 1, c = (gi & 1) * 8 + cjj;
#pragma unroll
          for (int w4 = 0; w4 < 4; ++w4) s += parts[w4][cb >> 4][fi][cb & 15][c];
          g[gi] = s;
        }
        const float i_ = sigf(g[0]), f_ = sigf(g[1]), gg = tanhf(g[2]), o_ = sigf(g[3]);
        creg = f_ * creg + i_ * gg;
        const unsigned short hv = f2bf(o_ * tanhf(creg));
        // recurrence copy: block-major, volatile, single-writer lines
        *(volatile unsigned short*)&hseq1[(size_t)t * BH + blk * 256 + tid] = hv;
        // GEMM copy: row-major, plain cached store (flushed at kernel end)
        hs_all[(size_t)t * BH + (size_t)cb * HH + jb + cjj] = hv;
      }
    }
    if (t < TT - 1) flagbar3(flags, epoch, (unsigned int)(t + 1));
  }
}

// ---------------- host ----------------

extern "C" void kernel_launch(void* const* d_in, const int* in_sizes, int n_in,
                              void* d_out, int out_size, void* d_ws, size_t ws_size,
                              hipStream_t stream) {
  const int* captions = (const int*)d_in[1];
  const float* etab = (const float*)d_in[2];
  const float* pos = (const float*)d_in[3];
  const float* Wih0 = (const float*)d_in[4];
  const float* Whh0 = (const float*)d_in[5];
  const float* bih0 = (const float*)d_in[6];
  const float* bhh0 = (const float*)d_in[7];
  const float* Wih1 = (const float*)d_in[8];
  const float* Whh1 = (const float*)d_in[9];
  const float* bih1 = (const float*)d_in[10];
  const float* bhh1 = (const float*)d_in[11];
  const float* Wout = (const float*)d_in[12];
  const float* bout = (const float*)d_in[13];
  float* out = (float*)d_out;

  char* w = (char*)d_ws;
  auto alloc = [&](size_t bytes) {
    char* p = w;
    w += (bytes + 255) & ~(size_t)255;
    return p;
  };
  // layout: flags(32KB) epoch(1KB) h0seq(8MB) hseq1(8MB) hs_all ...
  unsigned int* flags = (unsigned int*)alloc((size_t)NBLK * 128);
  unsigned int* epoch = (unsigned int*)alloc(1024);
  unsigned short* h0seq = (unsigned short*)alloc((size_t)TT * BH * 2);   // block-major
  unsigned short* hseq1 = (unsigned short*)alloc((size_t)TT * BH * 2);   // block-major
  unsigned short* hs_all = (unsigned short*)alloc((size_t)4160 * HH * 2);// row-major

  unsigned short* Xb = (unsigned short*)alloc((size_t)MPAD * EE * 2);
  unsigned short* Wih0b = (unsigned short*)alloc((size_t)FH * EE * 2);
  unsigned short* Woutb = (unsigned short*)alloc((size_t)VV * HH * 2);
  float* G0pre = (float*)alloc((size_t)MROWS * FH * 4);

  // 1) zero read-before-write state: flags+epoch+h0seq[slot0] (contiguous span)
  //    and hseq1[slot0]
  const int span0 = (NBLK * 128 + 1024 + BH * 2) / 16;
  hipLaunchKernelGGL(zero_k, dim3(25), dim3(256), 0, stream, (uint4*)flags, span0);
  hipLaunchKernelGGL(zero_k, dim3(16), dim3(256), 0, stream, (uint4*)hseq1,
                     (int)((BH * 2) / 16));
  // 2) convert Wih0 / Wout to bf16
  hipLaunchKernelGGL(cvt_bf16_v4, dim3(1024), dim3(256), 0, stream, (const float4*)Wih0,
                     (u16x4*)Wih0b, FH * EE / 4);
  hipLaunchKernelGGL(cvt_bf16_v4, dim3(4096), dim3(256), 0, stream, (const float4*)Wout,
                     (u16x4*)Woutb, VV * HH / 4);
  // 3) embeddings + pos -> X
  hipLaunchKernelGGL(embed_k, dim3(MPAD), dim3(256), 0, stream, captions, etab, pos, Xb);
  // 4) G0pre = X @ Wih0^T + bih0 + bhh0
  hipLaunchKernelGGL(gemm_bt, dim3(32, 32), dim3(256), 0, stream, Xb, Wih0b, EE, FH, 0, bih0,
                     bhh0, G0pre);
  // 5) persistent recurrence (one launch, 128 phases)
  hipLaunchKernelGGL(lstm_persist, dim3(NBLK), dim3(256), 0, stream, Whh0, Wih1, Whh1, G0pre,
                     bih1, bhh1, h0seq, hseq1, hs_all, flags, epoch);
  // 6) projection: logits = hs @ Wout^T + bout
  hipLaunchKernelGGL(gemm_bt, dim3(32, 250), dim3(256), 0, stream, hs_all + (size_t)BH, Woutb,
                     HH, VV, 1, bout, nullptr, out);
  // 7) out[:, 0, :] = 0
  hipLaunchKernelGGL(zero_out_t0, dim3(125, 32), dim3(256), 0, stream, out);
}